// Round 6
// baseline (70.045 us; speedup 1.0000x reference)
//
#include <hip/hip_runtime.h>

// out[i] = sum_b sum_t X[b, (i - t) mod D] * Y[b, t],  B=128, D=1024, fp32.
//
// Kernel 1 (cc_partial): grid 2048 = (b=128) x (tslice=16 of 64 t), 256 thr
//   (4 waves/block, 8 blocks/CU -> 32 waves/CU, two pipelined generations).
//   - X[b,:] staged 2x-replicated in LDS (8 KB), PLAIN layout: window reads
//     are consecutive-float4 b128 (16 B lane stride = canonical conflict-free
//     pattern; no pad/swizzle needed).
//   - Y: one coalesced 64-float load pre-barrier (lane l holds y[t0+l]);
//     inner loop broadcasts via v_readlane with compile-time lane. Zero
//     in-loop memory ops besides the X window.
//   - Thread tid: 4 outputs i = 4*tid..+3 over all 64 block t's; sliding
//     12-float register window, 2 new b128 per 8 t (17 b128 total).
//   - NO epilogue reduction: thread owns its outputs -> single transposed
//     b128 store ws4[tid][blk]. One barrier total. ~30 VGPR.
// Kernel 2 (cc_reduce): 256 blocks x 256 thr; block j reads ws4 row j
//   (2048 float4 = 32 KB contiguous, coalesced), 8 float4/thread, wave
//   butterfly, out4[j]. No atomics, no memset.

#define CC_D 1024

__device__ __forceinline__ float bcast(float v, int lane) {
  return __int_as_float(__builtin_amdgcn_readlane(__float_as_int(v), lane));
}

__global__ __launch_bounds__(256, 8) void cc_partial_kernel(
    const float* __restrict__ X, const float* __restrict__ Y,
    float* __restrict__ ws) {
  const int blk    = blockIdx.x;    // 0..2047
  const int b      = blk >> 4;      // 0..127
  const int tslice = blk & 15;      // 64 t's each
  const int tid    = threadIdx.x;   // 0..255
  const int lane   = tid & 63;

  __shared__ __align__(16) float4 sm4[512];   // x row replicated 2x (8 KB)

  const int t0 = tslice * 64;

  // Coalesced staging load + y lane load; latency hides under the barrier.
  const float4 xv   = ((const float4*)(X + b * CC_D))[tid];
  const float ymine = Y[b * CC_D + t0 + lane];   // lane l -> y[t0 + l]
  sm4[tid]       = xv;
  sm4[tid + 256] = xv;
  __syncthreads();

  // Group g (t = t0 + 8g + r): W[j] = xsh[4*(fbase - 2g) + j], j = 0..11;
  // acc[q] += W[8 + q - r] * y[8g + r]   (q in 0..3, r in 0..7).
  const int fbase = tid + 254 - 16 * tslice;   // float4 index, g = 0

  float W[12];
  {
    const float4 w0 = sm4[fbase];
    const float4 w1 = sm4[fbase + 1];
    const float4 w2 = sm4[fbase + 2];
    W[0] = w0.x; W[1]  = w0.y; W[2]  = w0.z; W[3]  = w0.w;
    W[4] = w1.x; W[5]  = w1.y; W[6]  = w1.z; W[7]  = w1.w;
    W[8] = w2.x; W[9]  = w2.y; W[10] = w2.z; W[11] = w2.w;
  }

  float4 acc = make_float4(0.f, 0.f, 0.f, 0.f);

#pragma unroll
  for (int g = 0; g < 8; ++g) {
#pragma unroll
    for (int r = 0; r < 8; ++r) {
      const float ybc = bcast(ymine, 8 * g + r);   // v_readlane, const lane
      acc.x += W[8 - r]  * ybc;
      acc.y += W[9 - r]  * ybc;
      acc.z += W[10 - r] * ybc;
      acc.w += W[11 - r] * ybc;
    }
    if (g < 7) {
      // slide window down 8 floats (2 float4)
      W[8] = W[0]; W[9] = W[1]; W[10] = W[2]; W[11] = W[3];
      const float4 w0 = sm4[fbase - 2 * (g + 1)];
      const float4 w1 = sm4[fbase - 2 * (g + 1) + 1];
      W[0] = w0.x; W[1] = w0.y; W[2] = w0.z; W[3] = w0.w;
      W[4] = w1.x; W[5] = w1.y; W[6] = w1.z; W[7] = w1.w;
    }
  }

  // Transposed partial store: ws4[i4 = tid][blk]; k2 reads contiguous rows.
  ((float4*)ws)[(size_t)tid * 2048 + blk] = acc;
}

__global__ __launch_bounds__(256) void cc_reduce_kernel(
    const float* __restrict__ ws, float* __restrict__ out) {
  const int j   = blockIdx.x;        // outputs 4j..4j+3
  const int tid = threadIdx.x;
  const int l   = tid & 63;
  const int w   = tid >> 6;          // wave 0..3

  __shared__ float4 red[4];

  const float4* row = (const float4*)ws + (size_t)j * 2048;
  float4 s = make_float4(0.f, 0.f, 0.f, 0.f);
#pragma unroll
  for (int c = 0; c < 8; ++c) {
    const float4 v = row[(size_t)(c * 256 + tid)];
    s.x += v.x; s.y += v.y; s.z += v.z; s.w += v.w;
  }
#pragma unroll
  for (int o = 32; o > 0; o >>= 1) {
    s.x += __shfl_xor(s.x, o, 64);
    s.y += __shfl_xor(s.y, o, 64);
    s.z += __shfl_xor(s.z, o, 64);
    s.w += __shfl_xor(s.w, o, 64);
  }
  if (l == 0) red[w] = s;
  __syncthreads();

  if (tid == 0) {
    float4 r = red[0];
    r.x += red[1].x + red[2].x + red[3].x;
    r.y += red[1].y + red[2].y + red[3].y;
    r.z += red[1].z + red[2].z + red[3].z;
    r.w += red[1].w + red[2].w + red[3].w;
    ((float4*)out)[j] = r;
  }
}

extern "C" void kernel_launch(void* const* d_in, const int* in_sizes, int n_in,
                              void* d_out, int out_size, void* d_ws,
                              size_t ws_size, hipStream_t stream) {
  const float* X = (const float*)d_in[0];  // (128, 1024) f32
  const float* Y = (const float*)d_in[1];  // (128, 1024) f32
  float* out = (float*)d_out;              // 1024 f32
  float* ws  = (float*)d_ws;               // 8 MB used

  cc_partial_kernel<<<2048, 256, 0, stream>>>(X, Y, ws);
  cc_reduce_kernel<<<256, 256, 0, stream>>>(ws, out);
}

// Round 7
// 66.910 us; speedup vs baseline: 1.0469x; 1.0469x over previous
//
#include <hip/hip_runtime.h>

// out[i] = sum_b sum_t X[b, (i - t) mod D] * Y[b, t],  B=128, D=1024, fp32.
//
// Kernel 1 (cc_partial): grid 256 = (b=128) x (thalf=2 of 512 t), 1024 thr
//   (16 waves/block, 1 block/CU, 16 waves/CU). Fat blocks: X row staged
//   only 2x total (vs 16x in R6) -> minimal redundant staging/instructions.
//   - X[b,:] 2x-replicated in LDS (8 KB), plain layout: window reads are
//     consecutive-float4 b128 (16 B lane stride, conflict-free).
//   - Thread (ig = tid&255, q = tid>>8): outputs i = 4*ig..+3 over the
//     128 t's of quarter q. y held in 2 lane regs, broadcast by
//     v_readlane (compile-time lane). Zero in-loop global ops.
//   - Sliding 12-float window, 2 new b128 per 8 t (35 b128 total).
//   - q-reduce through LDS (16 KB), then transposed store ws4[ig*256+blk]
//     -> k2 reads contiguous 4 KB rows. ws total = 1 MB (L2-resident).
// Kernel 2 (cc_reduce): 256 blocks x 256 thr; block j reads ws4 row j
//   (256 f4, coalesced), one f4/thread, wave butterfly, out4[j].

#define CC_D 1024

__device__ __forceinline__ float bcast(float v, int lane) {
  return __int_as_float(__builtin_amdgcn_readlane(__float_as_int(v), lane));
}

__global__ __launch_bounds__(1024, 4) void cc_partial_kernel(
    const float* __restrict__ X, const float* __restrict__ Y,
    float* __restrict__ ws) {
  const int blk   = blockIdx.x;    // 0..255
  const int b     = blk >> 1;      // 0..127
  const int thalf = blk & 1;       // 512 t's each
  const int tid   = threadIdx.x;   // 0..1023
  const int ig    = tid & 255;     // outputs i = 4*ig .. 4*ig+3
  const int q     = tid >> 8;      // 0..3: 128-t quarter (uniform per wave)
  const int lane  = tid & 63;

  __shared__ __align__(16) float smem[4096];   // 16 KB
  float4* sm4 = (float4*)smem;                 // X area: first 512 f4 (8 KB)

  const int t0 = thalf * 512 + q * 128;

  // Stage X row 2x (512 f4 writes by tid<512; redundant loads hit L1) and
  // per-lane y regs; global latency hides under the barrier.
  if (tid < 512) sm4[tid] = ((const float4*)(X + b * CC_D))[tid & 255];
  const float y0 = Y[b * CC_D + t0 + lane];
  const float y1 = Y[b * CC_D + t0 + 64 + lane];
  __syncthreads();

  // Group g (t = t0 + 8g + r): W[j] = xsh[4*fb(g) + j], j = 0..11,
  // fb(g) = 254 + ig - (t0>>2) - 2g.  acc[c] += W[8 + c - r] * y[8g + r].
  const int fb0 = 254 + ig - (t0 >> 2);

  float W[12];
  {
    const float4 w0 = sm4[fb0];
    const float4 w1 = sm4[fb0 + 1];
    const float4 w2 = sm4[fb0 + 2];
    W[0] = w0.x; W[1]  = w0.y; W[2]  = w0.z; W[3]  = w0.w;
    W[4] = w1.x; W[5]  = w1.y; W[6]  = w1.z; W[7]  = w1.w;
    W[8] = w2.x; W[9]  = w2.y; W[10] = w2.z; W[11] = w2.w;
  }

  float4 acc = make_float4(0.f, 0.f, 0.f, 0.f);

#pragma unroll
  for (int g = 0; g < 16; ++g) {
    const float ysrc = (g < 8) ? y0 : y1;
#pragma unroll
    for (int r = 0; r < 8; ++r) {
      const float ybc = bcast(ysrc, 8 * (g & 7) + r);  // const-lane readlane
      acc.x += W[8 - r]  * ybc;
      acc.y += W[9 - r]  * ybc;
      acc.z += W[10 - r] * ybc;
      acc.w += W[11 - r] * ybc;
    }
    if (g < 15) {
      W[8] = W[0]; W[9] = W[1]; W[10] = W[2]; W[11] = W[3];
      const float4 w0 = sm4[fb0 - 2 * (g + 1)];
      const float4 w1 = sm4[fb0 - 2 * (g + 1) + 1];
      W[0] = w0.x; W[1] = w0.y; W[2] = w0.z; W[3] = w0.w;
      W[4] = w1.x; W[5] = w1.y; W[6] = w1.z; W[7] = w1.w;
    }
  }

  // Reduce over the 4 t-quarters through LDS (X area no longer needed).
  __syncthreads();
  ((float4*)smem)[q * 256 + ig] = acc;
  __syncthreads();

  if (tid < 256) {
    const float4 s0 = ((const float4*)smem)[tid];
    const float4 s1 = ((const float4*)smem)[256 + tid];
    const float4 s2 = ((const float4*)smem)[512 + tid];
    const float4 s3 = ((const float4*)smem)[768 + tid];
    float4 s;
    s.x = (s0.x + s1.x) + (s2.x + s3.x);
    s.y = (s0.y + s1.y) + (s2.y + s3.y);
    s.z = (s0.z + s1.z) + (s2.z + s3.z);
    s.w = (s0.w + s1.w) + (s2.w + s3.w);
    // transposed: ws4[i4 = tid][blk] -> k2 reads contiguous 4 KB rows
    ((float4*)ws)[(size_t)tid * 256 + blk] = s;
  }
}

__global__ __launch_bounds__(256) void cc_reduce_kernel(
    const float* __restrict__ ws, float* __restrict__ out) {
  const int j   = blockIdx.x;        // outputs 4j..4j+3
  const int tid = threadIdx.x;
  const int l   = tid & 63;
  const int w   = tid >> 6;          // wave 0..3

  __shared__ float4 red[4];

  float4 s = ((const float4*)ws)[(size_t)j * 256 + tid];
#pragma unroll
  for (int o = 32; o > 0; o >>= 1) {
    s.x += __shfl_xor(s.x, o, 64);
    s.y += __shfl_xor(s.y, o, 64);
    s.z += __shfl_xor(s.z, o, 64);
    s.w += __shfl_xor(s.w, o, 64);
  }
  if (l == 0) red[w] = s;
  __syncthreads();

  if (tid == 0) {
    float4 r = red[0];
    r.x += red[1].x + red[2].x + red[3].x;
    r.y += red[1].y + red[2].y + red[3].y;
    r.z += red[1].z + red[2].z + red[3].z;
    r.w += red[1].w + red[2].w + red[3].w;
    ((float4*)out)[j] = r;
  }
}

extern "C" void kernel_launch(void* const* d_in, const int* in_sizes, int n_in,
                              void* d_out, int out_size, void* d_ws,
                              size_t ws_size, hipStream_t stream) {
  const float* X = (const float*)d_in[0];  // (128, 1024) f32
  const float* Y = (const float*)d_in[1];  // (128, 1024) f32
  float* out = (float*)d_out;              // 1024 f32
  float* ws  = (float*)d_ws;               // 1 MB used

  cc_partial_kernel<<<256, 1024, 0, stream>>>(X, Y, ws);
  cc_reduce_kernel<<<256, 256, 0, stream>>>(ws, out);
}